// Round 15
// baseline (105.398 us; speedup 1.0000x reference)
//
#include <hip/hip_runtime.h>

typedef _Float16 half8_t __attribute__((ext_vector_type(8)));
typedef _Float16 half4_t __attribute__((ext_vector_type(4)));
typedef float    float4_t __attribute__((ext_vector_type(4)));

// ---------------- ws layout (f16 elements unless noted) ----------------
// [0, 18432)        qkF   frag-order q,k weights:
//                   qkF[((f*3+kt)*64+lane)*8+j] = W_qkv[(kt*32+(lane>>4)*8+j)*288 + f*16+(lane&15)], f in [0,12)
// [18432, 27648)    vB    frag-order v-weights:
//                   vB[((f6*3+kt)*64+lane)*8+j] = W_qkv[(kt*32+(lane>>4)*8+j)*288 + 192+f6*16+(lane&15)]
// [27648, 36864)    woutB frag-order Wout (kt-pairs):
//                   woutB[((mt*3+kp)*64+lane)*8+s] = W_out[((2*kp+(s>>2))*16+(lane>>4)*4+(s&3))*96 + mt*16+(lane&15)]
// [36864 f16 = 73728 B, 77824 B)  biasT f32 [4][16][16]: biasT[m][j][i] = bias_m[i][j]
#define VB_OFF 18432
#define WOUTB_OFF 27648
#define BIAST_OFF_B 73728

__global__ void prep_kernel(const float* __restrict__ Wqkv,
                            const float* __restrict__ Wout,
                            const float* __restrict__ pos,
                            _Float16* __restrict__ wsh,
                            float* __restrict__ biasT) {
  int idx = blockIdx.x * 256 + threadIdx.x;
  if (idx < 18432) {
    int j = idx & 7, lane = (idx >> 3) & 63, fk = idx >> 9;   // fk in [0,36)
    int f = fk / 3, kt = fk % 3;
    int l15 = lane & 15, g = lane >> 4;
    int k = kt * 32 + g * 8 + j;                // input feature
    int fo = f * 16 + l15;                      // q,k output feature row
    wsh[idx] = (_Float16)Wqkv[k * 288 + fo];
  } else if (idx < 27648) {
    int t = idx - VB_OFF;
    int j = t & 7, lane = (t >> 3) & 63, fk = t >> 9;         // fk in [0,18)
    int f6 = fk / 3, kt = fk % 3;
    int l15 = lane & 15, g = lane >> 4;
    int k = kt * 32 + g * 8 + j;
    int fo = 192 + f6 * 16 + l15;               // v output feature row
    wsh[idx] = (_Float16)Wqkv[k * 288 + fo];
  } else if (idx < 36864) {
    int t = idx - WOUTB_OFF;
    int s = t & 7, lane = (t >> 3) & 63, fk = t >> 9;         // fk in [0,18)
    int mt = fk / 3, kp = fk % 3;
    int l15 = lane & 15, g = lane >> 4;
    int kt = kp * 2 + (s >> 2), j = s & 3;
    int k = kt * 16 + g * 4 + j;                // attn feature
    int fo = mt * 16 + l15;                     // out feature
    wsh[idx] = (_Float16)Wout[k * 96 + fo];
  } else if (idx < 36864 + 1024) {
    int t = idx - 36864;
    int m = t >> 8, j = (t >> 4) & 15, i = t & 15;            // store [j][i] = bias[i][j]
    int xi = i >> 2, yi = i & 3, xj = j >> 2, yj = j & 3;
    float v = pos[(xj - xi + 3) * 7 + (yj - yi + 3)];         // key minus query
    if ((m & 1) && ((i >= 8) != (j >= 8))) v -= 1e9f;         // ul mask (last window row)
    if ((m & 2) && ((yi >= 2) != (yj >= 2))) v -= 1e9f;       // lr mask (last window col)
    biasT[t] = v;
  }
}

static __device__ __forceinline__ half4_t pack4(float4_t a) {
  half4_t h;
  h[0] = (_Float16)a[0]; h[1] = (_Float16)a[1];
  h[2] = (_Float16)a[2]; h[3] = (_Float16)a[3];
  return h;
}

static __device__ __forceinline__ void gload_lds16(const void* g, void* l) {
  __builtin_amdgcn_global_load_lds(
      (const __attribute__((address_space(1))) unsigned int*)g,
      (__attribute__((address_space(3))) unsigned int*)l, 16, 0, 0);
}

// 512-thread blocks (8 waves), FOUR windows/wave interleaved, PER-HEAD
// scheduling: head h computes its 4 qk tiles + 2 v tiles per window, runs
// attention immediately, accumulates only ao (6 tiles/win live). 4 independent
// MFMA chains per load; qk/v frag loads amortized over 4 windows. All weights
// in LDS (73728 B, r12-proven). launch_bounds(512,2): cap 256 >= ~190 peak
// demand -> no spill (LDS caps residency at 8 waves/CU regardless).
__global__ __launch_bounds__(512, 2)
void swin_fused(const float* __restrict__ x,
                const _Float16* __restrict__ wsh,
                const float* __restrict__ biasT,
                const float* __restrict__ b_out,
                float* __restrict__ out) {
  __shared__ _Float16 wL[36864];   // 73728 B: qkF | vB | woutB, frag-order
  const int tid  = threadIdx.x;
  const int wave = tid >> 6;
  const int lane = tid & 63;
  const int l15  = lane & 15;
  const int g    = lane >> 4;
  const int ty = l15 >> 2, tx = l15 & 3;

  const int gwin  = blockIdx.x * 32 + wave * 4;  // flat window index (4/wave)
  const int batch = gwin / 784;
  const int wid0  = gwin % 784;                  // 784%4==0 -> same batch

  // per-window token positions (cyclic shift folded in; reused for stores)
  int pp[4], qq[4];
#pragma unroll
  for (int w = 0; w < 4; ++w) {
    int wid = wid0 + w;
    int wrow = wid / 28, wcol = wid % 28;
    int p = wrow * 4 + ty + 2; if (p >= 112) p -= 112;
    int q = wcol * 4 + tx + 2; if (q >= 112) q -= 112;
    pp[w] = p; qq[w] = q;
  }

  // ---- issue x loads (24 independent dwordx4)
  float4_t xa[4][3], xb[4][3];
#pragma unroll
  for (int w = 0; w < 4; ++w) {
    const float* xr = x + (((size_t)batch * 112 + pp[w]) * 112 + qq[w]) * 96 + g * 8;
#pragma unroll
    for (int kt = 0; kt < 3; ++kt) {
      xa[w][kt] = *(const float4_t*)(xr + kt * 32);
      xb[w][kt] = *(const float4_t*)(xr + kt * 32 + 4);
    }
  }

  // ---- async stage ALL weight frags (4608 chunks = 9 iters x 512 thr exact)
  {
    const char* gs = (const char*)wsh;
    char* lb = (char*)wL;
#pragma unroll
    for (int k = 0; k < 9; ++k) {
      int cb = k * 512 + wave * 64;          // wave-uniform chunk base
      size_t off = (size_t)(cb + lane) * 16;
      gload_lds16(gs + off, lb + off);
    }
  }

  // ---- per-window bias values
  float bb0[4], bb1[4], bb2[4], bb3[4];
#pragma unroll
  for (int w = 0; w < 4; ++w) {
    int wid = wid0 + w;
    int var = ((wid / 28) == 27 ? 1 : 0) + ((wid % 28) == 27 ? 2 : 0);
    const float* bt = biasT + var * 256 + g * 64 + l15;   // [var][j=4g+r][i=l15]
    bb0[w] = bt[0]; bb1[w] = bt[16]; bb2[w] = bt[32]; bb3[w] = bt[48];
  }

  // ---- convert x to f16 fragments
  half8_t xf[4][3];
#pragma unroll
  for (int w = 0; w < 4; ++w)
#pragma unroll
    for (int kt = 0; kt < 3; ++kt) {
      half8_t h;
      h[0] = (_Float16)xa[w][kt][0]; h[1] = (_Float16)xa[w][kt][1];
      h[2] = (_Float16)xa[w][kt][2]; h[3] = (_Float16)xa[w][kt][3];
      h[4] = (_Float16)xb[w][kt][0]; h[5] = (_Float16)xb[w][kt][1];
      h[6] = (_Float16)xb[w][kt][2]; h[7] = (_Float16)xb[w][kt][3];
      xf[w][kt] = h;
    }

  __syncthreads();   // staging complete (barrier drains vmcnt incl. global_load_lds)

  const _Float16* qkF = wL;
  const _Float16* vF  = wL + VB_OFF;
  const _Float16* woF = wL + WOUTB_OFF;
  const float scale = 0.17677669529663687f;  // 32^-0.5

  half4_t ao[4][6];   // attn outputs, accumulated per head (persistent)

  // ================= per-head: GEMM1(q,k,v) -> attn -> PV =================
#pragma unroll
  for (int h = 0; h < 3; ++h) {
    // ---- q,k tiles for this head: q f = 2h+t, k f = 6+2h+t (t=0,1)
    half4_t qk[4][4];   // [win][t] q tiles, [win][2+t] k tiles
#pragma unroll
    for (int t = 0; t < 2; ++t) {
      const int fq = 2 * h + t, fk = 6 + 2 * h + t;
      half8_t wq0 = *(const half8_t*)&qkF[((fq * 3 + 0) * 64 + lane) * 8];
      half8_t wq1 = *(const half8_t*)&qkF[((fq * 3 + 1) * 64 + lane) * 8];
      half8_t wq2 = *(const half8_t*)&qkF[((fq * 3 + 2) * 64 + lane) * 8];
      half8_t wk0 = *(const half8_t*)&qkF[((fk * 3 + 0) * 64 + lane) * 8];
      half8_t wk1 = *(const half8_t*)&qkF[((fk * 3 + 1) * 64 + lane) * 8];
      half8_t wk2 = *(const half8_t*)&qkF[((fk * 3 + 2) * 64 + lane) * 8];
#pragma unroll
      for (int w = 0; w < 4; ++w) {
        float4_t aq = {0.f, 0.f, 0.f, 0.f};
        aq = __builtin_amdgcn_mfma_f32_16x16x32_f16(wq0, xf[w][0], aq, 0, 0, 0);
        aq = __builtin_amdgcn_mfma_f32_16x16x32_f16(wq1, xf[w][1], aq, 0, 0, 0);
        aq = __builtin_amdgcn_mfma_f32_16x16x32_f16(wq2, xf[w][2], aq, 0, 0, 0);
        qk[w][t] = pack4(aq);
        float4_t ak = {0.f, 0.f, 0.f, 0.f};
        ak = __builtin_amdgcn_mfma_f32_16x16x32_f16(wk0, xf[w][0], ak, 0, 0, 0);
        ak = __builtin_amdgcn_mfma_f32_16x16x32_f16(wk1, xf[w][1], ak, 0, 0, 0);
        ak = __builtin_amdgcn_mfma_f32_16x16x32_f16(wk2, xf[w][2], ak, 0, 0, 0);
        qk[w][2 + t] = pack4(ak);
      }
    }
    // ---- v tiles for this head: f6 = 2h+t
    half4_t vt[4][2];
#pragma unroll
    for (int t = 0; t < 2; ++t) {
      const int f6 = 2 * h + t;
      half8_t vb0 = *(const half8_t*)&vF[((f6 * 3 + 0) * 64 + lane) * 8];
      half8_t vb1 = *(const half8_t*)&vF[((f6 * 3 + 1) * 64 + lane) * 8];
      half8_t vb2 = *(const half8_t*)&vF[((f6 * 3 + 2) * 64 + lane) * 8];
#pragma unroll
      for (int w = 0; w < 4; ++w) {
        float4_t av = {0.f, 0.f, 0.f, 0.f};
        av = __builtin_amdgcn_mfma_f32_16x16x32_f16(xf[w][0], vb0, av, 0, 0, 0);
        av = __builtin_amdgcn_mfma_f32_16x16x32_f16(xf[w][1], vb1, av, 0, 0, 0);
        av = __builtin_amdgcn_mfma_f32_16x16x32_f16(xf[w][2], vb2, av, 0, 0, 0);
        vt[w][t] = pack4(av);
      }
    }

    // ---- QK^T + exp (no max-subtract; masked = -1e9 -> exp 0), 4 windows
    float ps[4][4], ss[4];
#pragma unroll
    for (int w = 0; w < 4; ++w) {
      float4_t dd = {0.f, 0.f, 0.f, 0.f};
      dd = __builtin_amdgcn_mfma_f32_16x16x16f16(qk[w][2], qk[w][0], dd, 0, 0, 0);
      dd = __builtin_amdgcn_mfma_f32_16x16x16f16(qk[w][3], qk[w][1], dd, 0, 0, 0);
      ps[w][0] = __expf(fmaf(dd[0], scale, bb0[w]));
      ps[w][1] = __expf(fmaf(dd[1], scale, bb1[w]));
      ps[w][2] = __expf(fmaf(dd[2], scale, bb2[w]));
      ps[w][3] = __expf(fmaf(dd[3], scale, bb3[w]));
      ss[w] = (ps[w][0] + ps[w][1]) + (ps[w][2] + ps[w][3]);
    }
    // 4 independent cross-lane reduces, one latency exposure each level
#pragma unroll
    for (int w = 0; w < 4; ++w) ss[w] += __shfl_xor(ss[w], 16, 64);
#pragma unroll
    for (int w = 0; w < 4; ++w) ss[w] += __shfl_xor(ss[w], 32, 64);

    // ---- PV into persistent ao tiles
#pragma unroll
    for (int w = 0; w < 4; ++w) {
      float r = __builtin_amdgcn_rcpf(ss[w]);
      half4_t pb;   // P^T: B operand (col=query l15, k=key 4g+r)
      pb[0] = (_Float16)(ps[w][0] * r); pb[1] = (_Float16)(ps[w][1] * r);
      pb[2] = (_Float16)(ps[w][2] * r); pb[3] = (_Float16)(ps[w][3] * r);
      float4_t o0 = {0.f, 0.f, 0.f, 0.f};
      o0 = __builtin_amdgcn_mfma_f32_16x16x16f16(vt[w][0], pb, o0, 0, 0, 0);
      ao[w][2 * h] = pack4(o0);
      float4_t o1 = {0.f, 0.f, 0.f, 0.f};
      o1 = __builtin_amdgcn_mfma_f32_16x16x16f16(vt[w][1], pb, o1, 0, 0, 0);
      ao[w][2 * h + 1] = pack4(o1);
    }
  }

  // ================= GEMM3, 4-way interleaved; Wout frags from LDS =========
  float* orow[4];
#pragma unroll
  for (int w = 0; w < 4; ++w)
    orow[w] = out + (((size_t)batch * 112 + pp[w]) * 112 + qq[w]) * 96;
#pragma unroll
  for (int mt = 0; mt < 6; ++mt) {
    float4_t a0 = {0.f, 0.f, 0.f, 0.f};
    float4_t a1 = {0.f, 0.f, 0.f, 0.f};
    float4_t a2 = {0.f, 0.f, 0.f, 0.f};
    float4_t a3 = {0.f, 0.f, 0.f, 0.f};
#pragma unroll
    for (int kp = 0; kp < 3; ++kp) {
      half8_t wp = *(const half8_t*)&woF[((mt * 3 + kp) * 64 + lane) * 8];
      half4_t lo = __builtin_shufflevector(wp, wp, 0, 1, 2, 3);
      half4_t hi = __builtin_shufflevector(wp, wp, 4, 5, 6, 7);
      a0 = __builtin_amdgcn_mfma_f32_16x16x16f16(lo, ao[0][2 * kp],     a0, 0, 0, 0);
      a1 = __builtin_amdgcn_mfma_f32_16x16x16f16(lo, ao[1][2 * kp],     a1, 0, 0, 0);
      a2 = __builtin_amdgcn_mfma_f32_16x16x16f16(lo, ao[2][2 * kp],     a2, 0, 0, 0);
      a3 = __builtin_amdgcn_mfma_f32_16x16x16f16(lo, ao[3][2 * kp],     a3, 0, 0, 0);
      a0 = __builtin_amdgcn_mfma_f32_16x16x16f16(hi, ao[0][2 * kp + 1], a0, 0, 0, 0);
      a1 = __builtin_amdgcn_mfma_f32_16x16x16f16(hi, ao[1][2 * kp + 1], a1, 0, 0, 0);
      a2 = __builtin_amdgcn_mfma_f32_16x16x16f16(hi, ao[2][2 * kp + 1], a2, 0, 0, 0);
      a3 = __builtin_amdgcn_mfma_f32_16x16x16f16(hi, ao[3][2 * kp + 1], a3, 0, 0, 0);
    }
    float4_t bb = *(const float4_t*)&b_out[mt * 16 + g * 4];
    a0[0] += bb[0]; a0[1] += bb[1]; a0[2] += bb[2]; a0[3] += bb[3];
    a1[0] += bb[0]; a1[1] += bb[1]; a1[2] += bb[2]; a1[3] += bb[3];
    a2[0] += bb[0]; a2[1] += bb[1]; a2[2] += bb[2]; a2[3] += bb[3];
    a3[0] += bb[0]; a3[1] += bb[1]; a3[2] += bb[2]; a3[3] += bb[3];
    *(float4_t*)&orow[0][mt * 16 + g * 4] = a0;
    *(float4_t*)&orow[1][mt * 16 + g * 4] = a1;
    *(float4_t*)&orow[2][mt * 16 + g * 4] = a2;
    *(float4_t*)&orow[3][mt * 16 + g * 4] = a3;
  }
}

extern "C" void kernel_launch(void* const* d_in, const int* in_sizes, int n_in,
                              void* d_out, int out_size, void* d_ws, size_t ws_size,
                              hipStream_t stream) {
  const float* x    = (const float*)d_in[0];
  const float* Wqkv = (const float*)d_in[1];
  const float* pos  = (const float*)d_in[2];
  const float* Wout = (const float*)d_in[3];
  const float* bout = (const float*)d_in[4];
  char* ws = (char*)d_ws;
  _Float16* wsh  = (_Float16*)ws;
  float* biasT = (float*)(ws + BIAST_OFF_B);

  prep_kernel<<<148, 256, 0, stream>>>(Wqkv, Wout, pos, wsh, biasT);
  swin_fused<<<784, 512, 0, stream>>>(x, wsh, biasT, bout, (float*)d_out);
}

// Round 16
// 99.438 us; speedup vs baseline: 1.0599x; 1.0599x over previous
//
#include <hip/hip_runtime.h>

typedef _Float16 half8_t __attribute__((ext_vector_type(8)));
typedef _Float16 half4_t __attribute__((ext_vector_type(4)));
typedef float    float4_t __attribute__((ext_vector_type(4)));

// ---------------- ws layout (f16 elements unless noted) ----------------
// [0, 18432)        qkF   frag-order q,k weights:
//                   qkF[((f*3+kt)*64+lane)*8+j] = W_qkv[(kt*32+(lane>>4)*8+j)*288 + f*16+(lane&15)], f in [0,12)
// [18432, 27648)    vB    frag-order v-weights:
//                   vB[((f6*3+kt)*64+lane)*8+j] = W_qkv[(kt*32+(lane>>4)*8+j)*288 + 192+f6*16+(lane&15)]
// [27648, 36864)    woutB frag-order Wout (kt-pairs):
//                   woutB[((mt*3+kp)*64+lane)*8+s] = W_out[((2*kp+(s>>2))*16+(lane>>4)*4+(s&3))*96 + mt*16+(lane&15)]
// [36864 f16 = 73728 B, 77824 B)  biasT f32 [4][16][16]: biasT[m][j][i] = bias_m[i][j]
#define VB_OFF 18432
#define WOUTB_OFF 27648
#define BIAST_OFF_B 73728

__global__ void prep_kernel(const float* __restrict__ Wqkv,
                            const float* __restrict__ Wout,
                            const float* __restrict__ pos,
                            _Float16* __restrict__ wsh,
                            float* __restrict__ biasT) {
  int idx = blockIdx.x * 256 + threadIdx.x;
  if (idx < 18432) {
    int j = idx & 7, lane = (idx >> 3) & 63, fk = idx >> 9;   // fk in [0,36)
    int f = fk / 3, kt = fk % 3;
    int l15 = lane & 15, g = lane >> 4;
    int k = kt * 32 + g * 8 + j;                // input feature
    int fo = f * 16 + l15;                      // q,k output feature row
    wsh[idx] = (_Float16)Wqkv[k * 288 + fo];
  } else if (idx < 27648) {
    int t = idx - VB_OFF;
    int j = t & 7, lane = (t >> 3) & 63, fk = t >> 9;         // fk in [0,18)
    int f6 = fk / 3, kt = fk % 3;
    int l15 = lane & 15, g = lane >> 4;
    int k = kt * 32 + g * 8 + j;
    int fo = 192 + f6 * 16 + l15;               // v output feature row
    wsh[idx] = (_Float16)Wqkv[k * 288 + fo];
  } else if (idx < 36864) {
    int t = idx - WOUTB_OFF;
    int s = t & 7, lane = (t >> 3) & 63, fk = t >> 9;         // fk in [0,18)
    int mt = fk / 3, kp = fk % 3;
    int l15 = lane & 15, g = lane >> 4;
    int kt = kp * 2 + (s >> 2), j = s & 3;
    int k = kt * 16 + g * 4 + j;                // attn feature
    int fo = mt * 16 + l15;                     // out feature
    wsh[idx] = (_Float16)Wout[k * 96 + fo];
  } else if (idx < 36864 + 1024) {
    int t = idx - 36864;
    int m = t >> 8, j = (t >> 4) & 15, i = t & 15;            // store [j][i] = bias[i][j]
    int xi = i >> 2, yi = i & 3, xj = j >> 2, yj = j & 3;
    float v = pos[(xj - xi + 3) * 7 + (yj - yi + 3)];         // key minus query
    if ((m & 1) && ((i >= 8) != (j >= 8))) v -= 1e9f;         // ul mask (last window row)
    if ((m & 2) && ((yi >= 2) != (yj >= 2))) v -= 1e9f;       // lr mask (last window col)
    biasT[t] = v;
  }
}

static __device__ __forceinline__ half4_t pack4(float4_t a) {
  half4_t h;
  h[0] = (_Float16)a[0]; h[1] = (_Float16)a[1];
  h[2] = (_Float16)a[2]; h[3] = (_Float16)a[3];
  return h;
}

static __device__ __forceinline__ void gload_lds16(const void* g, void* l) {
  __builtin_amdgcn_global_load_lds(
      (const __attribute__((address_space(1))) unsigned int*)g,
      (__attribute__((address_space(3))) unsigned int*)l, 16, 0, 0);
}

// r12 dataflow (512 thr, 2 windows/wave interleaved, all weights in LDS) +
// amdgpu_waves_per_eu(4,4): LDS caps residency at ~4 waves/EU anyway, so tell
// the allocator the truth -> 128-VGPR budget instead of the 64 it was pinning
// (which re-serialized every unrolled loop). Explicit 1-deep rotating prefetch
// in each loop (load frags f+1 while computing f; chain crosses loop edges)
// gives the scheduler the pipelined shape to fill that budget.
__global__ __launch_bounds__(512)
__attribute__((amdgpu_waves_per_eu(4, 4)))
void swin_fused(const float* __restrict__ x,
                const _Float16* __restrict__ wsh,
                const float* __restrict__ biasT,
                const float* __restrict__ b_out,
                float* __restrict__ out) {
  __shared__ _Float16 wL[36864];   // 73728 B: qkF | vB | woutB, frag-order
  const int tid  = threadIdx.x;
  const int wave = tid >> 6;
  const int lane = tid & 63;
  const int l15  = lane & 15;
  const int g    = lane >> 4;
  const int ty = l15 >> 2, tx = l15 & 3;

  const int blk   = blockIdx.x;
  const int batch = blk / 49;
  const int wbase = (blk % 49) * 16 + wave * 2;   // this wave's 2 windows

  // per-window token positions (cyclic shift folded in; reused for stores)
  int pp[2], qq[2];
#pragma unroll
  for (int w = 0; w < 2; ++w) {
    int wid = wbase + w;
    int wrow = wid / 28, wcol = wid % 28;
    int p = wrow * 4 + ty + 2; if (p >= 112) p -= 112;
    int q = wcol * 4 + tx + 2; if (q >= 112) q -= 112;
    pp[w] = p; qq[w] = q;
  }

  // ---- issue x loads
  float4_t xa[2][3], xb[2][3];
#pragma unroll
  for (int w = 0; w < 2; ++w) {
    const float* xr = x + (((size_t)batch * 112 + pp[w]) * 112 + qq[w]) * 96 + g * 8;
#pragma unroll
    for (int kt = 0; kt < 3; ++kt) {
      xa[w][kt] = *(const float4_t*)(xr + kt * 32);
      xb[w][kt] = *(const float4_t*)(xr + kt * 32 + 4);
    }
  }

  // ---- async stage ALL weight frags (4608 16B chunks = 9 iters x 512 thr)
  {
    const char* gs = (const char*)wsh;
    char* lb = (char*)wL;
#pragma unroll
    for (int k = 0; k < 9; ++k) {
      int cb = k * 512 + wave * 64;          // wave-uniform chunk base
      size_t off = (size_t)(cb + lane) * 16;
      gload_lds16(gs + off, lb + off);
    }
  }

  // ---- per-window bias values
  float bb0[2], bb1[2], bb2[2], bb3[2];
#pragma unroll
  for (int w = 0; w < 2; ++w) {
    int wid = wbase + w;
    int var = ((wid / 28) == 27 ? 1 : 0) + ((wid % 28) == 27 ? 2 : 0);
    const float* bt = biasT + var * 256 + g * 64 + l15;   // [var][j=4g+r][i=l15]
    bb0[w] = bt[0]; bb1[w] = bt[16]; bb2[w] = bt[32]; bb3[w] = bt[48];
  }

  // ---- convert x to f16 fragments
  half8_t xf[2][3];
#pragma unroll
  for (int w = 0; w < 2; ++w)
#pragma unroll
    for (int kt = 0; kt < 3; ++kt) {
      half8_t h;
      h[0] = (_Float16)xa[w][kt][0]; h[1] = (_Float16)xa[w][kt][1];
      h[2] = (_Float16)xa[w][kt][2]; h[3] = (_Float16)xa[w][kt][3];
      h[4] = (_Float16)xb[w][kt][0]; h[5] = (_Float16)xb[w][kt][1];
      h[6] = (_Float16)xb[w][kt][2]; h[7] = (_Float16)xb[w][kt][3];
      xf[w][kt] = h;
    }

  __syncthreads();   // staging complete (barrier drains vmcnt incl. global_load_lds)

  const _Float16* qkF = wL;
  const _Float16* vF  = wL + VB_OFF;
  const _Float16* woF = wL + WOUTB_OFF;
  const float scale = 0.17677669529663687f;  // 32^-0.5

  // ---- GEMM1 qk tiles, interleaved + 1-deep rotating prefetch
  half4_t qk16[2][12];
  half8_t c0 = *(const half8_t*)&qkF[((0) * 64 + lane) * 8];
  half8_t c1 = *(const half8_t*)&qkF[((1) * 64 + lane) * 8];
  half8_t c2 = *(const half8_t*)&qkF[((2) * 64 + lane) * 8];
#pragma unroll
  for (int f = 0; f < 12; ++f) {
    half8_t n0, n1, n2;
    if (f < 11) {
      n0 = *(const half8_t*)&qkF[(((f + 1) * 3 + 0) * 64 + lane) * 8];
      n1 = *(const half8_t*)&qkF[(((f + 1) * 3 + 1) * 64 + lane) * 8];
      n2 = *(const half8_t*)&qkF[(((f + 1) * 3 + 2) * 64 + lane) * 8];
    } else {           // chain into the v loop
      n0 = *(const half8_t*)&vF[((0) * 64 + lane) * 8];
      n1 = *(const half8_t*)&vF[((1) * 64 + lane) * 8];
      n2 = *(const half8_t*)&vF[((2) * 64 + lane) * 8];
    }
    float4_t a0 = {0.f, 0.f, 0.f, 0.f};
    float4_t a1 = {0.f, 0.f, 0.f, 0.f};
    a0 = __builtin_amdgcn_mfma_f32_16x16x32_f16(c0, xf[0][0], a0, 0, 0, 0);
    a1 = __builtin_amdgcn_mfma_f32_16x16x32_f16(c0, xf[1][0], a1, 0, 0, 0);
    a0 = __builtin_amdgcn_mfma_f32_16x16x32_f16(c1, xf[0][1], a0, 0, 0, 0);
    a1 = __builtin_amdgcn_mfma_f32_16x16x32_f16(c1, xf[1][1], a1, 0, 0, 0);
    a0 = __builtin_amdgcn_mfma_f32_16x16x32_f16(c2, xf[0][2], a0, 0, 0, 0);
    a1 = __builtin_amdgcn_mfma_f32_16x16x32_f16(c2, xf[1][2], a1, 0, 0, 0);
    qk16[0][f] = pack4(a0);
    qk16[1][f] = pack4(a1);
    c0 = n0; c1 = n1; c2 = n2;
  }

  // ---- GEMM1 v tiles, interleaved + prefetch (c regs hold f6's vb frags)
  half4_t vt16[2][6];
#pragma unroll
  for (int f6 = 0; f6 < 6; ++f6) {
    half8_t n0, n1, n2;
    if (f6 < 5) {
      n0 = *(const half8_t*)&vF[(((f6 + 1) * 3 + 0) * 64 + lane) * 8];
      n1 = *(const half8_t*)&vF[(((f6 + 1) * 3 + 1) * 64 + lane) * 8];
      n2 = *(const half8_t*)&vF[(((f6 + 1) * 3 + 2) * 64 + lane) * 8];
    } else {           // chain into GEMM3: mt=0's three kp frags ride over attn
      n0 = *(const half8_t*)&woF[((0) * 64 + lane) * 8];
      n1 = *(const half8_t*)&woF[((1) * 64 + lane) * 8];
      n2 = *(const half8_t*)&woF[((2) * 64 + lane) * 8];
    }
    float4_t a0 = {0.f, 0.f, 0.f, 0.f};
    float4_t a1 = {0.f, 0.f, 0.f, 0.f};
    a0 = __builtin_amdgcn_mfma_f32_16x16x32_f16(xf[0][0], c0, a0, 0, 0, 0);
    a1 = __builtin_amdgcn_mfma_f32_16x16x32_f16(xf[1][0], c0, a1, 0, 0, 0);
    a0 = __builtin_amdgcn_mfma_f32_16x16x32_f16(xf[0][1], c1, a0, 0, 0, 0);
    a1 = __builtin_amdgcn_mfma_f32_16x16x32_f16(xf[1][1], c1, a1, 0, 0, 0);
    a0 = __builtin_amdgcn_mfma_f32_16x16x32_f16(xf[0][2], c2, a0, 0, 0, 0);
    a1 = __builtin_amdgcn_mfma_f32_16x16x32_f16(xf[1][2], c2, a1, 0, 0, 0);
    vt16[0][f6] = pack4(a0);
    vt16[1][f6] = pack4(a1);
    c0 = n0; c1 = n1; c2 = n2;
  }

  // ---- attention, interleaved: QK^T + exp (no max-subtract), batched shuffles
  float ps[2][3][4], ss[2][3];
#pragma unroll
  for (int h = 0; h < 3; ++h)
#pragma unroll
    for (int w = 0; w < 2; ++w) {
      float4_t dd = {0.f, 0.f, 0.f, 0.f};
      dd = __builtin_amdgcn_mfma_f32_16x16x16f16(qk16[w][6 + 2 * h], qk16[w][2 * h],     dd, 0, 0, 0);
      dd = __builtin_amdgcn_mfma_f32_16x16x16f16(qk16[w][7 + 2 * h], qk16[w][2 * h + 1], dd, 0, 0, 0);
      ps[w][h][0] = __expf(fmaf(dd[0], scale, bb0[w]));
      ps[w][h][1] = __expf(fmaf(dd[1], scale, bb1[w]));
      ps[w][h][2] = __expf(fmaf(dd[2], scale, bb2[w]));
      ps[w][h][3] = __expf(fmaf(dd[3], scale, bb3[w]));
      ss[w][h] = (ps[w][h][0] + ps[w][h][1]) + (ps[w][h][2] + ps[w][h][3]);
    }
  // 12 independent cross-lane reduces, one latency exposure
#pragma unroll
  for (int w = 0; w < 2; ++w)
#pragma unroll
    for (int h = 0; h < 3; ++h)
      ss[w][h] += __shfl_xor(ss[w][h], 16, 64);
#pragma unroll
  for (int w = 0; w < 2; ++w)
#pragma unroll
    for (int h = 0; h < 3; ++h)
      ss[w][h] += __shfl_xor(ss[w][h], 32, 64);

  half4_t ao[2][6];
#pragma unroll
  for (int h = 0; h < 3; ++h)
#pragma unroll
    for (int w = 0; w < 2; ++w) {
      float r = __builtin_amdgcn_rcpf(ss[w][h]);
      half4_t pb;   // P^T: B operand (col=query l15, k=key 4g+r)
      pb[0] = (_Float16)(ps[w][h][0] * r); pb[1] = (_Float16)(ps[w][h][1] * r);
      pb[2] = (_Float16)(ps[w][h][2] * r); pb[3] = (_Float16)(ps[w][h][3] * r);
      float4_t o0 = {0.f, 0.f, 0.f, 0.f};
      o0 = __builtin_amdgcn_mfma_f32_16x16x16f16(vt16[w][2 * h], pb, o0, 0, 0, 0);
      ao[w][2 * h] = pack4(o0);
      float4_t o1 = {0.f, 0.f, 0.f, 0.f};
      o1 = __builtin_amdgcn_mfma_f32_16x16x16f16(vt16[w][2 * h + 1], pb, o1, 0, 0, 0);
      ao[w][2 * h + 1] = pack4(o1);
    }

  // ---- GEMM3 interleaved + prefetch (c regs hold mt's three kp frags)
  float* orow0 = out + (((size_t)batch * 112 + pp[0]) * 112 + qq[0]) * 96;
  float* orow1 = out + (((size_t)batch * 112 + pp[1]) * 112 + qq[1]) * 96;
#pragma unroll
  for (int mt = 0; mt < 6; ++mt) {
    half8_t n0, n1, n2;
    if (mt < 5) {
      n0 = *(const half8_t*)&woF[(((mt + 1) * 3 + 0) * 64 + lane) * 8];
      n1 = *(const half8_t*)&woF[(((mt + 1) * 3 + 1) * 64 + lane) * 8];
      n2 = *(const half8_t*)&woF[(((mt + 1) * 3 + 2) * 64 + lane) * 8];
    }
    float4_t a0 = {0.f, 0.f, 0.f, 0.f};
    float4_t a1 = {0.f, 0.f, 0.f, 0.f};
    {
      half4_t lo = __builtin_shufflevector(c0, c0, 0, 1, 2, 3);
      half4_t hi = __builtin_shufflevector(c0, c0, 4, 5, 6, 7);
      a0 = __builtin_amdgcn_mfma_f32_16x16x16f16(lo, ao[0][0], a0, 0, 0, 0);
      a1 = __builtin_amdgcn_mfma_f32_16x16x16f16(lo, ao[1][0], a1, 0, 0, 0);
      a0 = __builtin_amdgcn_mfma_f32_16x16x16f16(hi, ao[0][1], a0, 0, 0, 0);
      a1 = __builtin_amdgcn_mfma_f32_16x16x16f16(hi, ao[1][1], a1, 0, 0, 0);
    }
    {
      half4_t lo = __builtin_shufflevector(c1, c1, 0, 1, 2, 3);
      half4_t hi = __builtin_shufflevector(c1, c1, 4, 5, 6, 7);
      a0 = __builtin_amdgcn_mfma_f32_16x16x16f16(lo, ao[0][2], a0, 0, 0, 0);
      a1 = __builtin_amdgcn_mfma_f32_16x16x16f16(lo, ao[1][2], a1, 0, 0, 0);
      a0 = __builtin_amdgcn_mfma_f32_16x16x16f16(hi, ao[0][3], a0, 0, 0, 0);
      a1 = __builtin_amdgcn_mfma_f32_16x16x16f16(hi, ao[1][3], a1, 0, 0, 0);
    }
    {
      half4_t lo = __builtin_shufflevector(c2, c2, 0, 1, 2, 3);
      half4_t hi = __builtin_shufflevector(c2, c2, 4, 5, 6, 7);
      a0 = __builtin_amdgcn_mfma_f32_16x16x16f16(lo, ao[0][4], a0, 0, 0, 0);
      a1 = __builtin_amdgcn_mfma_f32_16x16x16f16(lo, ao[1][4], a1, 0, 0, 0);
      a0 = __builtin_amdgcn_mfma_f32_16x16x16f16(hi, ao[0][5], a0, 0, 0, 0);
      a1 = __builtin_amdgcn_mfma_f32_16x16x16f16(hi, ao[1][5], a1, 0, 0, 0);
    }
    float4_t bb = *(const float4_t*)&b_out[mt * 16 + g * 4];
    a0[0] += bb[0]; a0[1] += bb[1]; a0[2] += bb[2]; a0[3] += bb[3];
    a1[0] += bb[0]; a1[1] += bb[1]; a1[2] += bb[2]; a1[3] += bb[3];
    *(float4_t*)&orow0[mt * 16 + g * 4] = a0;
    *(float4_t*)&orow1[mt * 16 + g * 4] = a1;
    if (mt < 5) { c0 = n0; c1 = n1; c2 = n2; }
  }
}

extern "C" void kernel_launch(void* const* d_in, const int* in_sizes, int n_in,
                              void* d_out, int out_size, void* d_ws, size_t ws_size,
                              hipStream_t stream) {
  const float* x    = (const float*)d_in[0];
  const float* Wqkv = (const float*)d_in[1];
  const float* pos  = (const float*)d_in[2];
  const float* Wout = (const float*)d_in[3];
  const float* bout = (const float*)d_in[4];
  char* ws = (char*)d_ws;
  _Float16* wsh  = (_Float16*)ws;
  float* biasT = (float*)(ws + BIAST_OFF_B);

  prep_kernel<<<148, 256, 0, stream>>>(Wqkv, Wout, pos, wsh, biasT);
  swin_fused<<<1568, 512, 0, stream>>>(x, wsh, biasT, bout, (float*)d_out);
}